// Round 1
// baseline (1287.034 us; speedup 1.0000x reference)
//
#include <hip/hip_runtime.h>
#include <math.h>

#define Q_SEG 100000
#define NGQ   5

// Gauss-Hermite 5-point nodes/weights (numpy.polynomial.hermite.hermgauss(5))
__device__ __forceinline__ void gh5(float* xk, float* wk) {
    xk[0] = -2.0201828704560856f; xk[1] = -0.9585724646138185f; xk[2] = 0.0f;
    xk[3] =  0.9585724646138185f; xk[4] =  2.0201828704560856f;
    wk[0] = 0.019953242059045913f; wk[1] = 0.3936193231522412f; wk[2] = 0.9453087204829419f;
    wk[3] = 0.3936193231522412f;   wk[4] = 0.019953242059045913f;
}

// Pass 1: per-element scatter-add of y*f, y, and softplus(f + ck) for each node.
__global__ void nll_pass1(const float* __restrict__ y_true,
                          const float* __restrict__ y_pred,
                          const int*   __restrict__ Z_idx,
                          const float* __restrict__ sig2b,
                          float* __restrict__ yf,
                          float* __restrict__ sy,
                          float* __restrict__ lg,   // [NGQ][Q_SEG]
                          int n) {
    float xk[NGQ], wk[NGQ];
    gh5(xk, wk);
    const float s = sqrtf(2.0f * sig2b[0]);

    int i = blockIdx.x * blockDim.x + threadIdx.x;
    if (i >= n) return;

    float y = y_true[i];
    float f = y_pred[i];
    int   q = Z_idx[i];
    if ((unsigned)q >= (unsigned)Q_SEG) return;  // safety guard

    if (y != 0.0f) {
        atomicAdd(&yf[q], y * f);
        atomicAdd(&sy[q], y);
    }
    #pragma unroll
    for (int k = 0; k < NGQ; ++k) {
        float x  = f + s * xk[k];
        // stable softplus: max(x,0) + log1p(exp(-|x|))
        float sp = fmaxf(x, 0.0f) + log1pf(expf(-fabsf(x)));
        atomicAdd(&lg[k * Q_SEG + q], sp);
    }
}

// Pass 2: per-segment stabilized log-sum-exp over 5 nodes, then global reduce.
__global__ void nll_pass2(const float* __restrict__ yf,
                          const float* __restrict__ sy,
                          const float* __restrict__ lg,
                          const float* __restrict__ sig2b,
                          float* __restrict__ out) {
    float xk[NGQ], wk[NGQ];
    gh5(xk, wk);
    const float s = sqrtf(2.0f * sig2b[0]);
    const float inv_sqrt_pi = 0.5641895835477563f;

    int q = blockIdx.x * blockDim.x + threadIdx.x;
    float contrib = 0.0f;
    if (q < Q_SEG) {
        float yfv = yf[q];
        float syv = sy[q];
        float a[NGQ];
        float m = -1e30f;
        #pragma unroll
        for (int k = 0; k < NGQ; ++k) {
            a[k] = yfv + syv * (s * xk[k]) - lg[k * Q_SEG + q];
            m = fmaxf(m, a[k]);
        }
        float ks = 0.0f;
        #pragma unroll
        for (int k = 0; k < NGQ; ++k) {
            ks += wk[k] * expf(a[k] - m);
        }
        // -log(k_sum) = -(m + log(ks * inv_sqrt_pi))
        contrib = -(m + logf(ks * inv_sqrt_pi));
    }

    // wave (64-lane) reduction
    #pragma unroll
    for (int off = 32; off > 0; off >>= 1)
        contrib += __shfl_down(contrib, off, 64);

    __shared__ float red[4];  // up to 4 waves per 256-thread block
    int lane = threadIdx.x & 63;
    int wid  = threadIdx.x >> 6;
    if (lane == 0) red[wid] = contrib;
    __syncthreads();
    if (threadIdx.x == 0) {
        float t = 0.0f;
        int nw = (blockDim.x + 63) >> 6;
        for (int w = 0; w < nw; ++w) t += red[w];
        atomicAdd(out, t);
    }
}

extern "C" void kernel_launch(void* const* d_in, const int* in_sizes, int n_in,
                              void* d_out, int out_size, void* d_ws, size_t ws_size,
                              hipStream_t stream) {
    const float* y_true = (const float*)d_in[0];
    const float* y_pred = (const float*)d_in[1];
    const int*   Z_idx  = (const int*)d_in[2];
    const float* sig2b  = (const float*)d_in[3];
    float* out = (float*)d_out;

    float* yf = (float*)d_ws;
    float* sy = yf + Q_SEG;
    float* lg = sy + Q_SEG;

    int n = in_sizes[0];  // N (y_true is (N,1))

    // ws/out are poisoned to 0xAA before every timed call — zero them here.
    hipMemsetAsync(d_ws, 0, (size_t)(2 + NGQ) * Q_SEG * sizeof(float), stream);
    hipMemsetAsync(d_out, 0, sizeof(float), stream);

    int threads = 256;
    int blocks1 = (n + threads - 1) / threads;
    nll_pass1<<<blocks1, threads, 0, stream>>>(y_true, y_pred, Z_idx, sig2b,
                                               yf, sy, lg, n);

    int blocks2 = (Q_SEG + threads - 1) / threads;
    nll_pass2<<<blocks2, threads, 0, stream>>>(yf, sy, lg, sig2b, out);
}